// Round 1
// baseline (747.947 us; speedup 1.0000x reference)
//
#include <hip/hip_runtime.h>

#define FEAT 41024
#define HID  256
#define BATCH 2048
#define MTOT 4096
#define MT 64
#define BK 64
#define NBK (FEAT / BK)                    /* 641 */
#define ACCN ((size_t)MTOT * HID)          /* 1,048,576 floats = 4 MB */
#define WH_BYTES ((size_t)HID * FEAT * 2)  /* 21,004,288 bytes, f16 W_in copy */

typedef float    f32x4  __attribute__((ext_vector_type(4)));
typedef float    f32x16 __attribute__((ext_vector_type(16)));
typedef _Float16 f16x4  __attribute__((ext_vector_type(4)));
typedef _Float16 f16x8  __attribute__((ext_vector_type(8)));

typedef const __attribute__((address_space(1))) unsigned int* gas1_t;
typedef __attribute__((address_space(3))) unsigned int*       las3_t;

__device__ __forceinline__ void gload_lds16(const void* g, void* l) {
    // direct-to-LDS DMA, 16 B per lane; LDS dest = wave-uniform base + lane*16
    __builtin_amdgcn_global_load_lds((gas1_t)g, (las3_t)l, 16, 0, 0);
}

// ---------------- zero kernel (atomic-fallback path only) ----------------
__global__ __launch_bounds__(512) void zero_ws_k(float* __restrict__ p) {
    int i = blockIdx.x * 512 + threadIdx.x;
    ((f32x4*)p)[i] = (f32x4)(0.0f);
}

// ---------------- W_in fp32 -> f16 one-shot convert (row-major copy) ----------------
__global__ __launch_bounds__(256) void cvt_w_k(
    const float* __restrict__ W, _Float16* __restrict__ Wh)
{
    const int n = (HID * FEAT) / 4;  // 2,625,536 f32x4 chunks
    for (int i = blockIdx.x * 256 + threadIdx.x; i < n; i += 256 * 1024) {
        f32x4 v = ((const f32x4*)W)[i];
        f16x4 h;
        #pragma unroll
        for (int e = 0; e < 4; ++e) h[e] = (_Float16)v[e];
        ((f16x4*)Wh)[i] = h;
    }
}

// ---------------- input-layer GEMM: [4096,41024] x [41024,256]^T ----------------
// 256 threads = 4 waves, block tile 64(M) x 256(N), wave tile 64x64 (2x2 of 32x32x16).
// A: reg-staged fp32->f16, double-buffered LDS (2x8 KB). B: f16, single 32 KB buffer,
// staged by global_load_lds (source pre-XOR-swizzled, linear LDS dest), fragments
// hoisted to regs before the buffer is overwritten. LDS 48 KB -> 3 blocks/CU.
__global__ __launch_bounds__(256, 3) void gemm_in_k(
    const float* __restrict__ wfeat, const float* __restrict__ bfeat,
    const _Float16* __restrict__ Wh, float* __restrict__ part,
    int ksplit, int use_atomic)
{
    __shared__ __align__(16) _Float16 As[2][MT * BK];   // 2 x 8 KB
    __shared__ __align__(16) _Float16 Bs[HID * BK];     // 32 KB

    const int tid   = threadIdx.x;
    const int mtile = blockIdx.x;
    const int split = blockIdx.y;
    const int it_beg = (split * NBK) / ksplit;
    const int it_end = ((split + 1) * NBK) / ksplit;

    const int m0 = mtile * MT;  // block entirely white or entirely black rows
    const float* Aptr = (m0 < BATCH) ? (wfeat + (size_t)m0 * FEAT)
                                     : (bfeat + (size_t)(m0 - BATCH) * FEAT);

    // A staging: thread -> (row 0..63, 16-float chunk 0..3)
    const int arow = tid >> 2;
    const int aqk  = tid & 3;
    const float* Asrc = Aptr + (size_t)arow * FEAT + aqk * 16;
    const int ac0 = (2 * aqk)     ^ (arow & 7);  // XOR-swizzled 16B-chunk slots
    const int ac1 = (2 * aqk + 1) ^ (arow & 7);

    // B staging via global_load_lds: slot s=(u*256+tid) <-> (r=s>>3, c=s&7);
    // source chunk = c ^ (r&7)  (constant per thread across u)
    const int brow0 = tid >> 3;                  // 0..31
    const int bcs   = (tid & 7) ^ (brow0 & 7);
    const _Float16* Bsrc = Wh + (size_t)brow0 * FEAT + bcs * 8;

    const int wid = tid >> 6, lane = tid & 63;
    const int l31 = lane & 31, lh = lane >> 5;
    _Float16* Bdst0 = &Bs[wid * 512];            // wave-uniform; + u*2048 elems per issue

    f32x16 acc[2][2];
    #pragma unroll
    for (int a = 0; a < 2; ++a)
        #pragma unroll
        for (int b = 0; b < 2; ++b)
            acc[a][b] = (f32x16)(0.0f);

    f32x4 pa[4];

    // ---- prologue: stage tile it_beg, prefetch A regs for it_beg+1 ----
    {
        const int k0 = it_beg * BK;
        f32x4 t0 = *(const f32x4*)(Asrc + k0);
        f32x4 t1 = *(const f32x4*)(Asrc + k0 + 4);
        f32x4 t2 = *(const f32x4*)(Asrc + k0 + 8);
        f32x4 t3 = *(const f32x4*)(Asrc + k0 + 12);
        f16x8 h0, h1;
        #pragma unroll
        for (int e = 0; e < 4; ++e) {
            h0[e] = (_Float16)t0[e]; h0[e + 4] = (_Float16)t1[e];
            h1[e] = (_Float16)t2[e]; h1[e + 4] = (_Float16)t3[e];
        }
        *(f16x8*)&As[0][arow * BK + ac0 * 8] = h0;
        *(f16x8*)&As[0][arow * BK + ac1 * 8] = h1;
        #pragma unroll
        for (int u = 0; u < 8; ++u)
            gload_lds16(Bsrc + (size_t)(u * 32) * FEAT + k0, Bdst0 + u * 2048);
        if (it_beg + 1 < it_end) {
            const float* s = Asrc + (size_t)(it_beg + 1) * BK;
            #pragma unroll
            for (int e = 0; e < 4; ++e) pa[e] = *(const f32x4*)(s + 4 * e);
        }
        __syncthreads();  // vmcnt drain: B DMA + A stage visible
    }

    int cur = 0;
    for (int it = it_beg; it < it_end; ++it) {
        // hoist B fragments to regs (Bs is overwritten right after barrier-1)
        f16x8 bfr[4][2];
        #pragma unroll
        for (int ks = 0; ks < 4; ++ks)
            #pragma unroll
            for (int nf = 0; nf < 2; ++nf) {
                const int r = wid * 64 + nf * 32 + l31;
                const int c = (ks * 2 + lh) ^ (r & 7);
                bfr[ks][nf] = *(const f16x8*)&Bs[r * BK + c * 8];
            }
        __syncthreads();  // barrier-1: all waves done reading Bs

        if (it + 1 < it_end) {
            const int kb = (it + 1) * BK;
            #pragma unroll
            for (int u = 0; u < 8; ++u)  // B tile it+1 -> Bs (DMA, lands under MFMA)
                gload_lds16(Bsrc + (size_t)(u * 32) * FEAT + kb, Bdst0 + u * 2048);
            // A tile it+1: cvt prefetched regs -> As[cur^1]
            _Float16* Ad = &As[cur ^ 1][0];
            f16x8 h0, h1;
            #pragma unroll
            for (int e = 0; e < 4; ++e) {
                h0[e] = (_Float16)pa[0][e]; h0[e + 4] = (_Float16)pa[1][e];
                h1[e] = (_Float16)pa[2][e]; h1[e + 4] = (_Float16)pa[3][e];
            }
            *(f16x8*)&Ad[arow * BK + ac0 * 8] = h0;
            *(f16x8*)&Ad[arow * BK + ac1 * 8] = h1;
            if (it + 2 < it_end) {  // reissue A prefetch for it+2
                const float* s = Asrc + (size_t)(it + 2) * BK;
                #pragma unroll
                for (int e = 0; e < 4; ++e) pa[e] = *(const f32x4*)(s + 4 * e);
            }
        }

        const _Float16* Ar = &As[cur][0];
        #pragma unroll
        for (int ks = 0; ks < 4; ++ks) {
            f16x8 afr[2];
            #pragma unroll
            for (int mf = 0; mf < 2; ++mf) {
                const int r = mf * 32 + l31;
                const int c = (ks * 2 + lh) ^ (r & 7);
                afr[mf] = *(const f16x8*)&Ar[r * BK + c * 8];
            }
            #pragma unroll
            for (int mf = 0; mf < 2; ++mf)
                #pragma unroll
                for (int nf = 0; nf < 2; ++nf)
                    acc[mf][nf] = __builtin_amdgcn_mfma_f32_32x32x16_f16(
                        afr[mf], bfr[ks][nf], acc[mf][nf], 0, 0, 0);
        }
        __syncthreads();  // barrier-2: B DMA drained, A writes visible
        cur ^= 1;
    }

    // epilogue: C/D layout col=lane&31, row=(reg&3)+8*(reg>>2)+4*(lane>>5)
    float* dst = part + (use_atomic ? (size_t)0 : (size_t)split * ACCN);
    #pragma unroll
    for (int mf = 0; mf < 2; ++mf)
        #pragma unroll
        for (int nf = 0; nf < 2; ++nf) {
            const int gcol = wid * 64 + nf * 32 + l31;
            #pragma unroll
            for (int r = 0; r < 16; ++r) {
                const int rrow = (r & 3) + 8 * (r >> 2) + 4 * lh;
                const int grow = m0 + mf * 32 + rrow;
                const size_t idx = (size_t)grow * HID + gcol;
                if (use_atomic) atomicAdd(&dst[idx], acc[mf][nf][r]);
                else            dst[idx] = acc[mf][nf][r];
            }
        }
}

// ---------------- split-K reduce + bias/relu + tiny MLP ----------------
// 256 blocks x 256 threads; wave handles 2 batch rows. Lane owns MLP output i=lane&31;
// half-waves split the 512-wide concat dimension.
__global__ __launch_bounds__(256) void mlp_k(
    const float* __restrict__ part, int nparts,
    const float* __restrict__ b_in,
    const float* __restrict__ W_h1, const float* __restrict__ b_h1,
    const float* __restrict__ W_h2, const float* __restrict__ b_h2,
    const float* __restrict__ W_out, const float* __restrict__ b_out,
    float* __restrict__ out)
{
    __shared__ _Float16 W1h[512 * 32];  // transposed [j][i], XOR-swizzled, 32 KB
    __shared__ float    W2T[32 * 33];   // transposed [ii][i'], padded
    __shared__ float    Wo[32];
    __shared__ float    cbuf[4 * 512];  // per-wave combined vector

    const int tid = threadIdx.x;
    #pragma unroll
    for (int u = 0; u < 64; ++u) {
        const int f = tid + 256 * u;
        const int i = f >> 9, j = f & 511;
        W1h[j * 32 + (i ^ (j & 31))] = (_Float16)W_h1[i * 512 + j];
    }
    #pragma unroll
    for (int u = 0; u < 4; ++u) {
        const int f = tid + 256 * u;
        const int a = f >> 5, b = f & 31;
        W2T[b * 33 + a] = W_h2[a * 32 + b];
    }
    if (tid < 32) Wo[tid] = W_out[tid];
    __syncthreads();

    const int wid = tid >> 6, lane = tid & 63, l31 = lane & 31, lh = lane >> 5;
    const float bh1 = b_h1[l31], bh2 = b_h2[l31], bo = b_out[0];
    float* cw = &cbuf[wid * 512];

    for (int r = 0; r < 2; ++r) {
        const int row = blockIdx.x * 8 + wid * 2 + r;
        const int jb  = lane * 8;  // 0..504; lanes 0-31 white half, 32-63 black half
        const size_t srow = (size_t)(lh ? (row + BATCH) : row) * HID + (jb & 255);
        f32x4 v0 = (f32x4)(0.0f), v1 = (f32x4)(0.0f);
        for (int s = 0; s < nparts; ++s) {
            const float* p = part + (size_t)s * ACCN + srow;
            v0 += *(const f32x4*)p;
            v1 += *(const f32x4*)(p + 4);
        }
        const f32x4 bi0 = *(const f32x4*)(b_in + (jb & 255));
        const f32x4 bi1 = *(const f32x4*)(b_in + (jb & 255) + 4);
        f32x4 c0, c1;
        #pragma unroll
        for (int e = 0; e < 4; ++e) {
            c0[e] = fmaxf(v0[e] + bi0[e], 0.0f);
            c1[e] = fmaxf(v1[e] + bi1[e], 0.0f);
        }
        *(f32x4*)&cw[jb]     = c0;
        *(f32x4*)&cw[jb + 4] = c1;
        __syncthreads();

        // x1[i] over 512-dim: half-waves handle j<256 / j>=256, then fold
        float p1 = 0.0f;
        #pragma unroll 8
        for (int jj = 0; jj < 256; ++jj) {
            const int j = lh * 256 + jj;
            p1 = fmaf((float)W1h[j * 32 + (l31 ^ (jj & 31))], cw[j], p1);
        }
        p1 += __shfl_xor(p1, 32);
        const float x1 = fmaxf(p1 + bh1, 0.0f);

        // x2[i'] = sum_i W_h2[i'][i] * x1[i], broadcast x1 via shfl
        float p2 = 0.0f;
        #pragma unroll
        for (int ii = 0; ii < 32; ++ii) {
            const float xv = __shfl(x1, ii);
            p2 = fmaf(W2T[ii * 33 + l31], xv, p2);
        }
        const float x2 = fmaxf(p2 + bh2, 0.0f);

        float ov = x2 * Wo[l31];
        ov += __shfl_xor(ov, 16);
        ov += __shfl_xor(ov, 8);
        ov += __shfl_xor(ov, 4);
        ov += __shfl_xor(ov, 2);
        ov += __shfl_xor(ov, 1);
        if (lane == 0) out[row] = ov + bo;
        __syncthreads();
    }
}

extern "C" void kernel_launch(void* const* d_in, const int* in_sizes, int n_in,
                              void* d_out, int out_size, void* d_ws, size_t ws_size,
                              hipStream_t stream) {
    const float* wf   = (const float*)d_in[0];
    const float* blf  = (const float*)d_in[1];
    const float* Win  = (const float*)d_in[2];
    const float* bin  = (const float*)d_in[3];
    const float* Wh1  = (const float*)d_in[4];
    const float* bh1  = (const float*)d_in[5];
    const float* Wh2  = (const float*)d_in[6];
    const float* bh2  = (const float*)d_in[7];
    const float* Wout = (const float*)d_in[8];
    const float* bout = (const float*)d_in[9];
    float* out = (float*)d_out;

    _Float16* Wh  = (_Float16*)d_ws;
    float*    part = (float*)((char*)d_ws + WH_BYTES);

    // ws-adaptive split count: 21 MB f16-W copy + ks * 4 MB partials
    int ks = 1, use_atomic = 0;
    if (ws_size >= WH_BYTES + ACCN * 4) {
        ks = (int)((ws_size - WH_BYTES) / (ACCN * 4));
        if (ks > 16) ks = 16;
    } else {
        use_atomic = 1;  // needs ws >= 25.2 MB (observed: >= 64 MB)
    }

    cvt_w_k<<<1024, 256, 0, stream>>>(Win, Wh);
    if (use_atomic) zero_ws_k<<<512, 512, 0, stream>>>(part);
    dim3 g(MTOT / MT, ks);
    gemm_in_k<<<g, 256, 0, stream>>>(wf, blf, Wh, part, ks, use_atomic);
    mlp_k<<<BATCH / 8, 256, 0, stream>>>(part, use_atomic ? 1 : ks,
                                         bin, Wh1, bh1, Wh2, bh2, Wout, bout, out);
}